// Round 17
// baseline (101.790 us; speedup 1.0000x reference)
//
#include <hip/hip_runtime.h>

#define N_ATOMS 262144
#define NGRAPH  2048
#define INV_SCALE 0.17677669529663687f  // 1/sqrt(32)

typedef float f32x2 __attribute__((ext_vector_type(2)));
typedef float f32x4 __attribute__((ext_vector_type(4)));

// CDNA packed fp32 (VOP3P), R5-verified.
__device__ __forceinline__ f32x2 pk_mul(f32x2 a, f32x2 b) {
  f32x2 d; asm("v_pk_mul_f32 %0, %1, %2" : "=v"(d) : "v"(a), "v"(b)); return d;
}
__device__ __forceinline__ f32x2 pk_fma(f32x2 a, f32x2 b, f32x2 c) {
  f32x2 d; asm("v_pk_fma_f32 %0, %1, %2, %3" : "=v"(d) : "v"(a), "v"(b), "v"(c)); return d;
}
__device__ __forceinline__ f32x2 pk_fma_blo(f32x2 a, f32x2 b, f32x2 c) {
  f32x2 d; asm("v_pk_fma_f32 %0, %1, %2, %3 op_sel_hi:[0,1,1]"
               : "=v"(d) : "v"(a), "v"(b), "v"(c)); return d;
}
__device__ __forceinline__ f32x2 pk_fma_bhi(f32x2 a, f32x2 b, f32x2 c) {
  f32x2 d; asm("v_pk_fma_f32 %0, %1, %2, %3 op_sel:[1,0,0]"
               : "=v"(d) : "v"(a), "v"(b), "v"(c)); return d;
}
__device__ __forceinline__ f32x4 ldnt4(const float* p) {
  return __builtin_nontemporal_load(reinterpret_cast<const f32x4*>(p));
}

// ---------------- K1: fused prep (blocks 0-7) + bounds (blocks 8-15).
__global__ void k_pre(const float* __restrict__ Wk, const float* __restrict__ bk,
                      const float* __restrict__ q, const int* __restrict__ batch,
                      float* __restrict__ P, float* __restrict__ c,
                      int* __restrict__ bounds) {
  if (blockIdx.x < 8) {
    int h = blockIdx.x, i = threadIdx.x;
    float s = 0.f;
    #pragma unroll
    for (int d = 0; d < 32; ++d)
      s = fmaf(Wk[i * 256 + h * 32 + d], q[h * 32 + d], s);
    P[h * 256 + i] = s;
    if (i == 0) {
      float cc = 0.f;
      #pragma unroll
      for (int d = 0; d < 32; ++d) cc = fmaf(bk[h * 32 + d], q[h * 32 + d], cc);
      c[h] = cc;
    }
  } else {
    int g = (blockIdx.x - 8) * 256 + threadIdx.x;
    if (g >= NGRAPH) return;
    int lo = 0, hi = N_ATOMS;
    while (lo < hi) {
      int mid = (lo + hi) >> 1;
      if (batch[mid] < g) lo = mid + 1; else hi = mid;
    }
    bounds[2 * g] = lo;
    if (g > 0) bounds[2 * g - 1] = lo;
    if (g == NGRAPH - 1) bounds[2 * g + 1] = N_ATOMS;
  }
}

// transpose-reduce: 8 head-partials/lane over 64 lanes -> full dot of head h at
// every lane (head h = 4*b3+2*b4+b5 of lane). R2/R8/R11-verified.
__device__ __forceinline__ float fold8(float acc[8], int lane) {
  {
    int m = lane & 8;
    float nw[4];
    #pragma unroll
    for (int j = 0; j < 4; ++j) {
      float snd = m ? acc[j] : acc[j + 4];
      float rcv = __shfl_xor(snd, 8, 64);
      nw[j] = (m ? acc[j + 4] : acc[j]) + rcv;
    }
    #pragma unroll
    for (int j = 0; j < 4; ++j) acc[j] = nw[j];
  }
  {
    int m = lane & 16;
    float nw[2];
    #pragma unroll
    for (int j = 0; j < 2; ++j) {
      float snd = m ? acc[j] : acc[j + 2];
      float rcv = __shfl_xor(snd, 16, 64);
      nw[j] = (m ? acc[j + 2] : acc[j]) + rcv;
    }
    acc[0] = nw[0]; acc[1] = nw[1];
  }
  float r;
  {
    int m = lane & 32;
    float snd = m ? acc[0] : acc[1];
    float rcv = __shfl_xor(snd, 32, 64);
    r = (m ? acc[1] : acc[0]) + rcv;
  }
  r += __shfl_xor(r, 1, 64);
  r += __shfl_xor(r, 2, 64);
  r += __shfl_xor(r, 4, 64);
  return r;
}

// ---------------- K2: fused scores + exp + weighted accumulate, SOFTWARE-
// PIPELINED at the algorithm level: atom g's ACCUMULATE is deferred one
// iteration, so iteration g does {accumulate(g-1); issue load(g+2) into the
// freed slot; dot+fold+exp(g)}. Loads get ~2 iterations to complete; x is no
// longer consumed at both ends of one serial chain. 3 static register slots
// (hand-unrolled x3, rule #20); e-values live in a 3-slot LDS table. Math is
// bit-identical to R11 (clamp+ev=0 masking lets the pipeline run unguarded).
__global__ __launch_bounds__(256, 4) void k_fused(const float* __restrict__ x,
                                                  const float* __restrict__ P,
                                                  const float* __restrict__ c,
                                                  const int* __restrict__ bounds,
                                                  float* __restrict__ Ag) {
  int b = blockIdx.x;
  int s = bounds[2 * b], e = bounds[2 * b + 1];
  int t = threadIdx.x, lane = t & 63, wv = t >> 6;
  int h = ((lane >> 1) & 4) | ((lane >> 3) & 2) | ((lane >> 5) & 1);

  f32x2 Pl2[8][2];
  #pragma unroll
  for (int k = 0; k < 8; ++k) {
    f32x4 pv = *reinterpret_cast<const f32x4*>(P + k * 256 + 4 * lane);
    Pl2[k][0] = __builtin_shufflevector(pv, pv, 0, 1);
    Pl2[k][1] = __builtin_shufflevector(pv, pv, 2, 3);
  }
  float cl = c[h];

  f32x2 A2[8][2];
  #pragma unroll
  for (int k = 0; k < 8; ++k) { A2[k][0] = (f32x2)0.f; A2[k][1] = (f32x2)0.f; }
  float dacc = 0.f;

  __shared__ float elds[4][3][8];   // wave-private e-table, 3 pipeline slots
  __shared__ float Asc[4][2][256];  // 8 KB chunked epilogue buffer
  __shared__ float dws[4][8];
  __shared__ float dinvs[8];

  const float* xl = x + 4 * lane;

  auto ca = [&](int a) { return a < e ? a : (e - 1); };

  // accumulate one atom: A2 += e[slot] * XQ  (16 pk_fma; R5-verified layout)
  auto acc_step = [&](f32x4 XQ, int ES) {
    f32x4 eA = *reinterpret_cast<const f32x4*>(&elds[wv][ES][0]);
    f32x4 eB = *reinterpret_cast<const f32x4*>(&elds[wv][ES][4]);
    f32x2 ep[4] = { __builtin_shufflevector(eA, eA, 0, 1),
                    __builtin_shufflevector(eA, eA, 2, 3),
                    __builtin_shufflevector(eB, eB, 0, 1),
                    __builtin_shufflevector(eB, eB, 2, 3) };
    f32x2 xlo = __builtin_shufflevector(XQ, XQ, 0, 1);
    f32x2 xhi = __builtin_shufflevector(XQ, XQ, 2, 3);
    #pragma unroll
    for (int j = 0; j < 4; ++j) {
      A2[2*j][0]   = pk_fma_blo(ep[j], xlo, A2[2*j][0]);
      A2[2*j][1]   = pk_fma_blo(ep[j], xhi, A2[2*j][1]);
      A2[2*j+1][0] = pk_fma_bhi(ep[j], xlo, A2[2*j+1][0]);
      A2[2*j+1][1] = pk_fma_bhi(ep[j], xhi, A2[2*j+1][1]);
    }
  };

  // dot+fold+exp one atom; mask out-of-range; publish e to slot ES
  auto dot_step = [&](f32x4 XQ, int ES, int aidx) {
    f32x2 xlo = __builtin_shufflevector(XQ, XQ, 0, 1);
    f32x2 xhi = __builtin_shufflevector(XQ, XQ, 2, 3);
    float acc[8];
    #pragma unroll
    for (int k = 0; k < 8; ++k) {
      f32x2 p = pk_fma(xhi, Pl2[k][1], pk_mul(xlo, Pl2[k][0]));
      acc[k] = p[0] + p[1];
    }
    float r = fold8(acc, lane);
    float ev = __expf((r + cl) * INV_SCALE);
    ev = (aidx < e) ? ev : 0.f;
    dacc += ev;
    if ((lane & 7) == 0) elds[wv][ES][h] = ev;
  };

  int i0 = s + wv;  // this wave's atoms: i0, i0+4, i0+8, ...
  if (i0 < e) {
    int G = (e - i0 + 3) >> 2;     // atoms this wave
    int M = (G + 3) / 3;           // groups: covers G dots + G accumulates
    f32x4 xqA = ldnt4(xl + (size_t)ca(i0) * 256);
    f32x4 xqB = ldnt4(xl + (size_t)ca(i0 + 4) * 256);
    f32x4 xqC = {0.f, 0.f, 0.f, 0.f};
    if ((lane & 7) == 0) elds[wv][2][h] = 0.f;  // "atom -1" contributes 0
    int a = i0;
    for (int m = 0; m < M; ++m) {
      // sub X: acc(a-4)@C, load(a+8)->C, dot(a)@A -> e-slot 0
      acc_step(xqC, 2);
      xqC = ldnt4(xl + (size_t)ca(a + 8) * 256);
      dot_step(xqA, 0, a);
      // sub Y: acc(a)@A, load(a+12)->A, dot(a+4)@B -> e-slot 1
      acc_step(xqA, 0);
      xqA = ldnt4(xl + (size_t)ca(a + 12) * 256);
      dot_step(xqB, 1, a + 4);
      // sub Z: acc(a+4)@B, load(a+16)->B, dot(a+8)@C -> e-slot 2
      acc_step(xqB, 1);
      xqB = ldnt4(xl + (size_t)ca(a + 16) * 256);
      dot_step(xqC, 2, a + 8);
      a += 12;
    }
  }

  // ---- epilogue: denom, then 4 head-pair passes of cross-wave reduce (R11).
  if ((lane & 7) == 0) dws[wv][h] = dacc;
  __syncthreads();
  if (t < 8) {
    float ds = dws[0][t] + dws[1][t] + dws[2][t] + dws[3][t];
    dinvs[t] = ds > 0.f ? 1.0f / ds : 0.f;
  }
  #pragma unroll
  for (int p = 0; p < 4; ++p) {
    float4 a0, a1;
    a0.x = A2[2*p][0][0];   a0.y = A2[2*p][0][1];
    a0.z = A2[2*p][1][0];   a0.w = A2[2*p][1][1];
    a1.x = A2[2*p+1][0][0]; a1.y = A2[2*p+1][0][1];
    a1.z = A2[2*p+1][1][0]; a1.w = A2[2*p+1][1][1];
    *reinterpret_cast<float4*>(&Asc[wv][0][4 * lane]) = a0;
    *reinterpret_cast<float4*>(&Asc[wv][1][4 * lane]) = a1;
    __syncthreads();
    float v0 = Asc[0][0][t] + Asc[1][0][t] + Asc[2][0][t] + Asc[3][0][t];
    float v1 = Asc[0][1][t] + Asc[1][1][t] + Asc[2][1][t] + Asc[3][1][t];
    Ag[(size_t)b * 2048 + (2*p) * 256 + t]   = v0 * dinvs[2*p];
    Ag[(size_t)b * 2048 + (2*p+1) * 256 + t] = v1 * dinvs[2*p+1];
    __syncthreads();
  }
}

// ---------------- K5: att = A . Wv + bv (nonempty), out = att . Wo + bo
__global__ __launch_bounds__(256) void k_out(const float* __restrict__ Ag,
                                             const int* __restrict__ bounds,
                                             const float* __restrict__ Wv,
                                             const float* __restrict__ bv,
                                             const float* __restrict__ Wo,
                                             const float* __restrict__ bo,
                                             float* __restrict__ out) {
  __shared__ float Alds[4 * 2048];   // 32 KB
  __shared__ float attlds[4 * 256];  // 4 KB
  __shared__ float eflag[4];
  int b0 = blockIdx.x * 4;
  int t = threadIdx.x;
  #pragma unroll
  for (int r = 0; r < 32; ++r) {
    int idx = r * 256 + t;
    Alds[idx] = Ag[(size_t)b0 * 2048 + idx];
  }
  if (t < 4) {
    int s = bounds[2 * (b0 + t)], e = bounds[2 * (b0 + t) + 1];
    eflag[t] = (e > s) ? 1.0f : 0.0f;
  }
  __syncthreads();
  int h = t >> 5;
  float bvk = bv[t];
  float acc[4];
  #pragma unroll
  for (int g = 0; g < 4; ++g) acc[g] = 0.f;
  for (int i4 = 0; i4 < 64; ++i4) {
    float aa[4][4];
    #pragma unroll
    for (int g = 0; g < 4; ++g) {
      float4 v = *reinterpret_cast<const float4*>(&Alds[g * 2048 + h * 256 + i4 * 4]);
      aa[g][0] = v.x; aa[g][1] = v.y; aa[g][2] = v.z; aa[g][3] = v.w;
    }
    #pragma unroll
    for (int j = 0; j < 4; ++j) {
      float wvv = Wv[(size_t)(i4 * 4 + j) * 256 + t];
      #pragma unroll
      for (int g = 0; g < 4; ++g) acc[g] = fmaf(aa[g][j], wvv, acc[g]);
    }
  }
  #pragma unroll
  for (int g = 0; g < 4; ++g) attlds[g * 256 + t] = acc[g] + bvk * eflag[g];
  __syncthreads();
  float boj = bo[t];
  float o[4];
  #pragma unroll
  for (int g = 0; g < 4; ++g) o[g] = boj;
  for (int k4 = 0; k4 < 64; ++k4) {
    float aa[4][4];
    #pragma unroll
    for (int g = 0; g < 4; ++g) {
      float4 v = *reinterpret_cast<const float4*>(&attlds[g * 256 + k4 * 4]);
      aa[g][0] = v.x; aa[g][1] = v.y; aa[g][2] = v.z; aa[g][3] = v.w;
    }
    #pragma unroll
    for (int j = 0; j < 4; ++j) {
      float wo = Wo[(size_t)(k4 * 4 + j) * 256 + t];
      #pragma unroll
      for (int g = 0; g < 4; ++g) o[g] = fmaf(aa[g][j], wo, o[g]);
    }
  }
  #pragma unroll
  for (int g = 0; g < 4; ++g) out[(size_t)(b0 + g) * 256 + t] = o[g];
}

extern "C" void kernel_launch(void* const* d_in, const int* in_sizes, int n_in,
                              void* d_out, int out_size, void* d_ws, size_t ws_size,
                              hipStream_t stream) {
  const float* x   = (const float*)d_in[0];
  const int*   bat = (const int*)d_in[1];
  const float* q   = (const float*)d_in[2];
  const float* Wk  = (const float*)d_in[3];
  const float* bk  = (const float*)d_in[4];
  const float* Wv  = (const float*)d_in[5];
  const float* bv  = (const float*)d_in[6];
  const float* Wo  = (const float*)d_in[7];
  const float* bo  = (const float*)d_in[8];
  float* out = (float*)d_out;

  float* ws = (float*)d_ws;
  float* P      = ws;                 // 2048 floats
  float* c      = ws + 2048;          // 8 floats
  int*   bounds = (int*)(ws + 4096);  // 4096 ints
  float* Ag     = ws + 8192;          // 2048*2048 floats

  k_pre<<<16, 256, 0, stream>>>(Wk, bk, q, bat, P, c, bounds);
  k_fused<<<NGRAPH, 256, 0, stream>>>(x, P, c, bounds, Ag);
  k_out<<<NGRAPH / 4, 256, 0, stream>>>(Ag, bounds, Wv, bv, Wo, bo, out);
}